// Round 8
// baseline (272.071 us; speedup 1.0000x reference)
//
#include <hip/hip_runtime.h>

#define NQ      4
#define DIMQ    16
#define D_MODEL 1024
#define TPB     16      // tokens per block: one token per 16-lane group
#define PI_F    3.14159265358979323846f

__global__ __launch_bounds__(256, 4)
void qffn_kernel(const float* __restrict__ x,
                 const float* __restrict__ Wi,
                 const float* __restrict__ bi,
                 const float* __restrict__ Wo,
                 const float* __restrict__ bo,
                 const float* __restrict__ fp,
                 float* __restrict__ out,
                 int n_tokens)
{
    const int tid  = threadIdx.x;
    const int lane = tid & 63;
    const int w    = tid >> 6;        // wave id (0..3)
    const int j    = lane & 15;       // lane within group: owns d-slice (i*16+j)*4
    const int g    = lane >> 4;       // group within wave (0..3)

    int tok = blockIdx.x * TPB + w * 4 + g;
    const int last = n_tokens - 1;
    if (tok > last) tok = last;

    const float4* x4  = (const float4*)x;
    const float4* Wi4 = (const float4*)Wi;
    const size_t  xbase = (size_t)tok * 256;

    // ---- dot phase: group of 16 lanes covers all 1024 d's of its token ----
    // per iter: 1 x-float4 + 4 contiguous Wi rows (64B cluster, L2-resident)
    float p0 = 0.f, p1 = 0.f, p2 = 0.f, p3 = 0.f;
    #pragma unroll 4
    for (int i = 0; i < 16; ++i) {
        const int s = i * 16 + j;                 // float4 index in token row
        float4 xv = x4[xbase + s];
        const float4* wr = Wi4 + ((size_t)s << 2); // Wi rows 4s..4s+3 (contiguous)
        float4 w0 = wr[0], w1 = wr[1], w2 = wr[2], w3 = wr[3];
        p0 = fmaf(xv.x, w0.x, p0); p1 = fmaf(xv.x, w0.y, p1); p2 = fmaf(xv.x, w0.z, p2); p3 = fmaf(xv.x, w0.w, p3);
        p0 = fmaf(xv.y, w1.x, p0); p1 = fmaf(xv.y, w1.y, p1); p2 = fmaf(xv.y, w1.z, p2); p3 = fmaf(xv.y, w1.w, p3);
        p0 = fmaf(xv.z, w2.x, p0); p1 = fmaf(xv.z, w2.y, p1); p2 = fmaf(xv.z, w2.z, p2); p3 = fmaf(xv.z, w2.w, p3);
        p0 = fmaf(xv.w, w3.x, p0); p1 = fmaf(xv.w, w3.y, p1); p2 = fmaf(xv.w, w3.z, p2); p3 = fmaf(xv.w, w3.w, p3);
    }

    // ---- 4-stage intra-group butterfly: every lane gets the token's full sums ----
    #pragma unroll
    for (int m = 1; m < 16; m <<= 1) {
        p0 += __shfl_xor(p0, m, 64);
        p1 += __shfl_xor(p1, m, 64);
        p2 += __shfl_xor(p2, m, 64);
        p3 += __shfl_xor(p3, m, 64);
    }

    const float xp0 = p0 + bi[0];
    const float xp1 = p1 + bi[1];
    const float xp2 = p2 + bi[2];
    const float xp3 = p3 + bi[3];

    // ---- angles ----
    float mn = fminf(fminf(xp0, xp1), fminf(xp2, xp3));
    float mx = fmaxf(fmaxf(xp0, xp1), fmaxf(xp2, xp3));
    float inv = PI_F / (mx - mn + 1e-8f);
    float ang[NQ];
    ang[0] = (xp0 - mn) * inv;
    ang[1] = (xp1 - mn) * inv;
    ang[2] = (xp2 - mn) * inv;
    ang[3] = (xp3 - mn) * inv;

    // ---- 4-qubit statevector sim, redundantly in all 16 lanes of the group ----
    float pc[NQ], ps[NQ];
    #pragma unroll
    for (int q = 0; q < NQ; ++q) {
        float h = 0.5f * fp[q];            // wave-uniform scalar loads
        pc[q] = __cosf(h);
        ps[q] = __sinf(h);
    }

    float sr[DIMQ], si[DIMQ];
    #pragma unroll
    for (int k = 0; k < DIMQ; ++k) { sr[k] = (k == 0) ? 1.0f : 0.0f; si[k] = 0.0f; }

    #pragma unroll
    for (int q = 0; q < NQ; ++q) {
        const int bit = 8 >> q;
        float h = 0.5f * ang[q];
        float cth = __cosf(h), sth = __sinf(h);
        #pragma unroll
        for (int k = 0; k < DIMQ; ++k) {
            if (!(k & bit)) {
                const int k1 = k | bit;
                float a0r = sr[k],  a0i = si[k];
                float a1r = sr[k1], a1i = si[k1];
                sr[k]  = fmaf(cth, a0r,  sth * a1i);
                si[k]  = fmaf(cth, a0i, -sth * a1r);
                sr[k1] = fmaf(cth, a1r,  sth * a0i);
                si[k1] = fmaf(cth, a1i, -sth * a0r);
            }
        }
    }
    #pragma unroll
    for (int q = 0; q < NQ; ++q) {
        const int bit = 8 >> q;
        float cth = pc[q], sth = ps[q];
        #pragma unroll
        for (int k = 0; k < DIMQ; ++k) {
            if (!(k & bit)) {
                const int k1 = k | bit;
                float a0r = sr[k],  a0i = si[k];
                float a1r = sr[k1], a1i = si[k1];
                sr[k]  = fmaf(cth, a0r,  sth * a1i);
                si[k]  = fmaf(cth, a0i, -sth * a1r);
                sr[k1] = fmaf(cth, a1r,  sth * a0i);
                si[k1] = fmaf(cth, a1i, -sth * a0r);
            }
        }
        const int cbit = 8 >> q;
        const int tbit = 8 >> ((q + 1) & 3);
        #pragma unroll
        for (int k = 0; k < DIMQ; ++k) {
            if ((k & cbit) && !(k & tbit)) {
                const int k1 = k | tbit;
                float t;
                t = sr[k]; sr[k] = sr[k1]; sr[k1] = t;
                t = si[k]; si[k] = si[k1]; si[k1] = t;
            }
        }
    }

    float pr[DIMQ];
    #pragma unroll
    for (int k = 0; k < DIMQ; ++k) pr[k] = fmaf(sr[k], sr[k], si[k] * si[k]);

    float qv0 = 0.f, qv1 = 0.f, qv2 = 0.f, qv3 = 0.f;
    #pragma unroll
    for (int k = 0; k < DIMQ; ++k) {
        qv0 += (k & 8) ? -pr[k] : pr[k];
        qv1 += (k & 4) ? -pr[k] : pr[k];
        qv2 += (k & 2) ? -pr[k] : pr[k];
        qv3 += (k & 1) ? -pr[k] : pr[k];
    }

    // ---- output: group writes its token's row; Wo/bo straight from L2 ----
    const float4* Wo4 = (const float4*)Wo;
    const float4* bo4 = (const float4*)bo;
    float4* out4 = (float4*)out;

    #pragma unroll 4
    for (int i = 0; i < 16; ++i) {
        const int c = i * 16 + j;
        float4 wa = Wo4[0 * 256 + c];
        float4 wb = Wo4[1 * 256 + c];
        float4 wc = Wo4[2 * 256 + c];
        float4 wd = Wo4[3 * 256 + c];
        float4 bb = bo4[c];
        float4 v;
        v.x = fmaf(qv0, wa.x, fmaf(qv1, wb.x, fmaf(qv2, wc.x, fmaf(qv3, wd.x, bb.x))));
        v.y = fmaf(qv0, wa.y, fmaf(qv1, wb.y, fmaf(qv2, wc.y, fmaf(qv3, wd.y, bb.y))));
        v.z = fmaf(qv0, wa.z, fmaf(qv1, wb.z, fmaf(qv2, wc.z, fmaf(qv3, wd.z, bb.z))));
        v.w = fmaf(qv0, wa.w, fmaf(qv1, wb.w, fmaf(qv2, wc.w, fmaf(qv3, wd.w, bb.w))));
        out4[xbase + c] = v;
    }
}

extern "C" void kernel_launch(void* const* d_in, const int* in_sizes, int n_in,
                              void* d_out, int out_size, void* d_ws, size_t ws_size,
                              hipStream_t stream)
{
    (void)d_ws; (void)ws_size; (void)n_in; (void)out_size;
    const float* x  = (const float*)d_in[0];
    const float* Wi = (const float*)d_in[1];
    const float* bi = (const float*)d_in[2];
    const float* Wo = (const float*)d_in[3];
    const float* bo = (const float*)d_in[4];
    const float* fp = (const float*)d_in[5];
    float* out = (float*)d_out;

    int n_tokens = in_sizes[0] / D_MODEL;
    int grid = (n_tokens + TPB - 1) / TPB;
    qffn_kernel<<<grid, 256, 0, stream>>>(x, Wi, bi, Wo, bo, fp, out, n_tokens);
}